// Round 1
// baseline (1732.895 us; speedup 1.0000x reference)
//
#include <hip/hip_runtime.h>
#include <math.h>

#define N_NODES 100000

// ---- degree / norm precompute ------------------------------------------------

__global__ void deg_kernel(const int* __restrict__ dst, float* __restrict__ deg, int E) {
    int i = blockIdx.x * blockDim.x + threadIdx.x;
    int stride = gridDim.x * blockDim.x;
    for (int e = i; e < E; e += stride)
        atomicAdd(&deg[dst[e]], 1.0f);
}

__global__ void dinv_kernel(const float* __restrict__ deg, float* __restrict__ dinv, int n) {
    int i = blockIdx.x * blockDim.x + threadIdx.x;
    if (i < n) dinv[i] = rsqrtf(deg[i] + 1.0f);   // +1 = self-loop
}

__global__ void norm_kernel(const int* __restrict__ src, const int* __restrict__ dst,
                            const float* __restrict__ dinv, float* __restrict__ norm, int E) {
    int i = blockIdx.x * blockDim.x + threadIdx.x;
    int stride = gridDim.x * blockDim.x;
    for (int e = i; e < E; e += stride)
        norm[e] = dinv[src[e]] * dinv[dst[e]];
}

// ---- per-layer dense GEMM, fused with self-loop init of the aggregator ------
// lin[i][f] = (h @ W)[i][f];  agg[i][f] = dinv[i]^2 * lin[i][f]

template<int FIN, int FOUT>
__global__ void gemm_selfinit(const float* __restrict__ h, const float* __restrict__ W,
                              const float* __restrict__ dinv,
                              float* __restrict__ lin, float* __restrict__ agg, int n) {
    __shared__ float sW[FIN * FOUT];
    for (int i = threadIdx.x; i < FIN * FOUT; i += blockDim.x) sW[i] = W[i];
    __syncthreads();
    constexpr int ROWS = 256 / FOUT;
    int f = threadIdx.x % FOUT;
    int r = threadIdx.x / FOUT;
    int row = blockIdx.x * ROWS + r;
    if (row >= n) return;
    const float* hr = h + (size_t)row * FIN;
    float acc = 0.f;
#pragma unroll
    for (int k = 0; k < FIN; ++k) acc = fmaf(hr[k], sW[k * FOUT + f], acc);
    float dv = dinv[row];
    size_t o = (size_t)row * FOUT + f;
    lin[o] = acc;
    agg[o] = dv * dv * acc;
}

// ---- edge aggregation: agg[dst] += norm * lin[src] ---------------------------
// FOUT lanes cooperate on one edge -> coalesced row gather + coalesced atomics.

template<int FOUT>
__global__ void scatter_edges(const int* __restrict__ src, const int* __restrict__ dst,
                              const float* __restrict__ norm, const float* __restrict__ lin,
                              float* __restrict__ agg, int E) {
    int tid = blockIdx.x * blockDim.x + threadIdx.x;
    int f = tid % FOUT;
    int eg = tid / FOUT;
    int stride = (gridDim.x * blockDim.x) / FOUT;
    for (int e = eg; e < E; e += stride) {
        int s = src[e];
        int d = dst[e];
        float w = norm[e];
        float v = lin[(size_t)s * FOUT + f];
        atomicAdd(&agg[(size_t)d * FOUT + f], w * v);
    }
}

// ---- bias + tanh -------------------------------------------------------------

template<int FOUT>
__global__ void bias_tanh(const float* __restrict__ agg, const float* __restrict__ b,
                          float* __restrict__ h, int n) {
    int idx = blockIdx.x * blockDim.x + threadIdx.x;
    if (idx < n * FOUT) {
        int f = idx % FOUT;
        h[idx] = tanhf(agg[idx] + b[f]);
    }
}

// ---- classifier: out = h @ Wc + bc  (8 -> 2) ---------------------------------

__global__ void classifier_kernel(const float* __restrict__ h, const float* __restrict__ Wc,
                                  const float* __restrict__ bc, float* __restrict__ out, int n) {
    int i = blockIdx.x * blockDim.x + threadIdx.x;
    if (i >= n) return;
    const float* hr = h + (size_t)i * 8;
    float a0 = bc[0], a1 = bc[1];
#pragma unroll
    for (int k = 0; k < 8; ++k) {
        float v = hr[k];
        a0 = fmaf(v, Wc[k * 2 + 0], a0);
        a1 = fmaf(v, Wc[k * 2 + 1], a1);
    }
    out[(size_t)i * 2 + 0] = a0;
    out[(size_t)i * 2 + 1] = a1;
}

// ---- launch ------------------------------------------------------------------

extern "C" void kernel_launch(void* const* d_in, const int* in_sizes, int n_in,
                              void* d_out, int out_size, void* d_ws, size_t ws_size,
                              hipStream_t stream) {
    const float* x  = (const float*)d_in[0];
    const int*   ei = (const int*)d_in[1];
    const float* W1 = (const float*)d_in[2];  const float* b1 = (const float*)d_in[3];
    const float* W2 = (const float*)d_in[4];  const float* b2 = (const float*)d_in[5];
    const float* W3 = (const float*)d_in[6];  const float* b3 = (const float*)d_in[7];
    const float* W4 = (const float*)d_in[8];  const float* b4 = (const float*)d_in[9];
    const float* Wc = (const float*)d_in[10]; const float* bc = (const float*)d_in[11];

    float* out  = (float*)d_out;                      // [N,2]
    float* hout = out + (size_t)2 * N_NODES;          // [N,8] (second tuple element)

    const int n = N_NODES;
    const int E = in_sizes[1] / 2;
    const int* src = ei;
    const int* dst = ei + E;

    float* ws   = (float*)d_ws;
    float* deg  = ws;  ws += n;
    float* dinv = ws;  ws += n;
    float* norm = ws;  ws += E;
    float* lin  = ws;  ws += (size_t)n * 64;
    float* agg  = ws;  ws += (size_t)n * 64;
    float* hA   = ws;  ws += (size_t)n * 64;
    float* hB   = ws;  ws += (size_t)n * 32;

    hipMemsetAsync(deg, 0, n * sizeof(float), stream);
    deg_kernel<<<2048, 256, 0, stream>>>(dst, deg, E);
    dinv_kernel<<<(n + 255) / 256, 256, 0, stream>>>(deg, dinv, n);
    norm_kernel<<<2048, 256, 0, stream>>>(src, dst, dinv, norm, E);

    // layer 1: x[34] -> hA[64]
    gemm_selfinit<34, 64><<<(n + 3) / 4, 256, 0, stream>>>(x, W1, dinv, lin, agg, n);
    scatter_edges<64><<<2048, 256, 0, stream>>>(src, dst, norm, lin, agg, E);
    bias_tanh<64><<<(n * 64 + 255) / 256, 256, 0, stream>>>(agg, b1, hA, n);

    // layer 2: hA[64] -> hB[32]
    gemm_selfinit<64, 32><<<(n + 7) / 8, 256, 0, stream>>>(hA, W2, dinv, lin, agg, n);
    scatter_edges<32><<<2048, 256, 0, stream>>>(src, dst, norm, lin, agg, E);
    bias_tanh<32><<<(n * 32 + 255) / 256, 256, 0, stream>>>(agg, b2, hB, n);

    // layer 3: hB[32] -> hA[16]
    gemm_selfinit<32, 16><<<(n + 15) / 16, 256, 0, stream>>>(hB, W3, dinv, lin, agg, n);
    scatter_edges<16><<<2048, 256, 0, stream>>>(src, dst, norm, lin, agg, E);
    bias_tanh<16><<<(n * 16 + 255) / 256, 256, 0, stream>>>(agg, b3, hA, n);

    // layer 4: hA[16] -> hout[8]  (h is the 2nd output, written in place)
    gemm_selfinit<16, 8><<<(n + 31) / 32, 256, 0, stream>>>(hA, W4, dinv, lin, agg, n);
    scatter_edges<8><<<2048, 256, 0, stream>>>(src, dst, norm, lin, agg, E);
    bias_tanh<8><<<(n * 8 + 255) / 256, 256, 0, stream>>>(agg, b4, hout, n);

    // classifier: out = hout @ Wc + bc
    classifier_kernel<<<(n + 255) / 256, 256, 0, stream>>>(hout, Wc, bc, out, n);
}

// Round 3
// 1141.700 us; speedup vs baseline: 1.5178x; 1.5178x over previous
//
#include <hip/hip_runtime.h>
#include <math.h>

#define N_NODES 100000

// ---- CSR build: degree histogram -> exclusive scan -> bucket fill ------------

__global__ void deg_kernel(const int* __restrict__ dst, int* __restrict__ deg, int E) {
    int i = blockIdx.x * blockDim.x + threadIdx.x;
    int stride = gridDim.x * blockDim.x;
    for (int e = i; e < E; e += stride)
        atomicAdd(&deg[dst[e]], 1);
}

__global__ void dinv_kernel(const int* __restrict__ deg, float* __restrict__ dinv, int n) {
    int i = blockIdx.x * blockDim.x + threadIdx.x;
    if (i < n) dinv[i] = rsqrtf((float)deg[i] + 1.0f);   // +1 = self-loop
}

// single-workgroup exclusive scan over n=100k degrees -> off[] and cursor[]
__global__ __launch_bounds__(1024) void scan_kernel(const int* __restrict__ deg,
                                                    int* __restrict__ off,
                                                    int* __restrict__ cursor, int n, int E) {
    __shared__ int part[1024];
    int t = threadIdx.x;
    int chunk = (n + 1023) / 1024;
    int lo = t * chunk, hi = min(lo + chunk, n);
    int s = 0;
    for (int i = lo; i < hi; ++i) s += deg[i];
    part[t] = s;
    __syncthreads();
    for (int d = 1; d < 1024; d <<= 1) {
        int u = (t >= d) ? part[t - d] : 0;
        __syncthreads();
        part[t] += u;
        __syncthreads();
    }
    int run = part[t] - s;   // exclusive base for this thread's chunk
    for (int i = lo; i < hi; ++i) {
        off[i] = run;
        cursor[i] = run;
        run += deg[i];
    }
    if (t == 1023) off[n] = E;
}

// fill CSR: for each edge, place (src, dinv[src]*dinv[dst]) into dst's bucket
__global__ void fill_csr(const int* __restrict__ src, const int* __restrict__ dst,
                         const float* __restrict__ dinv, int* __restrict__ cursor,
                         float2* __restrict__ csr, int E) {
    int i = blockIdx.x * blockDim.x + threadIdx.x;
    int stride = gridDim.x * blockDim.x;
    for (int e = i; e < E; e += stride) {
        int s = src[e];
        int d = dst[e];
        float w = dinv[s] * dinv[d];
        int pos = atomicAdd(&cursor[d], 1);
        csr[pos] = make_float2(__int_as_float(s), w);
    }
}

// ---- per-layer dense GEMM (lin = h @ W) --------------------------------------

template<int FIN, int FOUT>
__global__ void gemm_kernel(const float* __restrict__ h, const float* __restrict__ W,
                            float* __restrict__ lin, int n) {
    __shared__ float sW[FIN * FOUT];
    for (int i = threadIdx.x; i < FIN * FOUT; i += blockDim.x) sW[i] = W[i];
    __syncthreads();
    constexpr int ROWS = 256 / FOUT;
    int f = threadIdx.x % FOUT;
    int r = threadIdx.x / FOUT;
    int row = blockIdx.x * ROWS + r;
    if (row >= n) return;
    const float* hr = h + (size_t)row * FIN;
    float acc = 0.f;
#pragma unroll
    for (int k = 0; k < FIN; ++k) acc = fmaf(hr[k], sW[k * FOUT + f], acc);
    lin[(size_t)row * FOUT + f] = acc;
}

// ---- fused aggregation: h = tanh(dinv^2*lin[i] + sum_e w*lin[src] + b) -------
// FOUT lanes own one dst node; register accumulation; no atomics.

template<int FOUT>
__global__ void gather_tanh(const int* __restrict__ off, const float2* __restrict__ csr,
                            const float* __restrict__ lin, const float* __restrict__ dinv,
                            const float* __restrict__ b, float* __restrict__ h, int n) {
    constexpr int GPB = 256 / FOUT;
    int g = blockIdx.x * GPB + threadIdx.x / FOUT;
    int f = threadIdx.x % FOUT;
    if (g >= n) return;
    int rb = off[g], re = off[g + 1];
    float dv = dinv[g];
    float acc = dv * dv * lin[(size_t)g * FOUT + f];
#pragma unroll 2
    for (int e = rb; e < re; ++e) {
        float2 p = csr[e];
        int s = __float_as_int(p.x);
        acc = fmaf(p.y, lin[(size_t)s * FOUT + f], acc);
    }
    h[(size_t)g * FOUT + f] = tanhf(acc + b[f]);
}

// ---- classifier: out = h @ Wc + bc  (8 -> 2) ---------------------------------

__global__ void classifier_kernel(const float* __restrict__ h, const float* __restrict__ Wc,
                                  const float* __restrict__ bc, float* __restrict__ out, int n) {
    int i = blockIdx.x * blockDim.x + threadIdx.x;
    if (i >= n) return;
    const float* hr = h + (size_t)i * 8;
    float a0 = bc[0], a1 = bc[1];
#pragma unroll
    for (int k = 0; k < 8; ++k) {
        float v = hr[k];
        a0 = fmaf(v, Wc[k * 2 + 0], a0);
        a1 = fmaf(v, Wc[k * 2 + 1], a1);
    }
    out[(size_t)i * 2 + 0] = a0;
    out[(size_t)i * 2 + 1] = a1;
}

// ---- launch ------------------------------------------------------------------

extern "C" void kernel_launch(void* const* d_in, const int* in_sizes, int n_in,
                              void* d_out, int out_size, void* d_ws, size_t ws_size,
                              hipStream_t stream) {
    const float* x  = (const float*)d_in[0];
    const int*   ei = (const int*)d_in[1];
    const float* W1 = (const float*)d_in[2];  const float* b1 = (const float*)d_in[3];
    const float* W2 = (const float*)d_in[4];  const float* b2 = (const float*)d_in[5];
    const float* W3 = (const float*)d_in[6];  const float* b3 = (const float*)d_in[7];
    const float* W4 = (const float*)d_in[8];  const float* b4 = (const float*)d_in[9];
    const float* Wc = (const float*)d_in[10]; const float* bc = (const float*)d_in[11];

    float* out  = (float*)d_out;                      // [N,2]
    float* hout = out + (size_t)2 * N_NODES;          // [N,8]

    const int n = N_NODES;
    const int E = in_sizes[1] / 2;
    const int* src = ei;
    const int* dst = ei + E;

    char* w = (char*)d_ws;
    int*    deg    = (int*)w;     w += (size_t)n * 4;
    float*  dinv   = (float*)w;   w += (size_t)n * 4;
    int*    off    = (int*)w;     w += (size_t)(n + 1) * 4;
    int*    cursor = (int*)w;     w += (size_t)n * 4;
    float2* csr    = (float2*)w;  w += (size_t)E * 8;
    float*  lin    = (float*)w;   w += (size_t)n * 64 * 4;
    float*  hA     = (float*)w;   w += (size_t)n * 64 * 4;
    float*  hB     = (float*)w;   w += (size_t)n * 32 * 4;

    hipMemsetAsync(deg, 0, n * sizeof(int), stream);
    deg_kernel<<<2048, 256, 0, stream>>>(dst, deg, E);
    dinv_kernel<<<(n + 255) / 256, 256, 0, stream>>>(deg, dinv, n);
    scan_kernel<<<1, 1024, 0, stream>>>(deg, off, cursor, n, E);
    fill_csr<<<2048, 256, 0, stream>>>(src, dst, dinv, cursor, csr, E);

    // layer 1: x[34] -> hA[64]
    gemm_kernel<34, 64><<<(n + 3) / 4, 256, 0, stream>>>(x, W1, lin, n);
    gather_tanh<64><<<(n + 3) / 4, 256, 0, stream>>>(off, csr, lin, dinv, b1, hA, n);

    // layer 2: hA[64] -> hB[32]
    gemm_kernel<64, 32><<<(n + 7) / 8, 256, 0, stream>>>(hA, W2, lin, n);
    gather_tanh<32><<<(n + 7) / 8, 256, 0, stream>>>(off, csr, lin, dinv, b2, hB, n);

    // layer 3: hB[32] -> hA[16]
    gemm_kernel<32, 16><<<(n + 15) / 16, 256, 0, stream>>>(hB, W3, lin, n);
    gather_tanh<16><<<(n + 15) / 16, 256, 0, stream>>>(off, csr, lin, dinv, b3, hA, n);

    // layer 4: hA[16] -> hout[8]
    gemm_kernel<16, 8><<<(n + 31) / 32, 256, 0, stream>>>(hA, W4, lin, n);
    gather_tanh<8><<<(n + 31) / 32, 256, 0, stream>>>(off, csr, lin, dinv, b4, hout, n);

    // classifier
    classifier_kernel<<<(n + 255) / 256, 256, 0, stream>>>(hout, Wc, bc, out, n);
}

// Round 4
// 933.596 us; speedup vs baseline: 1.8562x; 1.2229x over previous
//
#include <hip/hip_runtime.h>
#include <math.h>

#define N_NODES 100000
#define SCAN_TILE 2048   // 256 threads x 8 elements

// ---- CSR build: degree histogram -> parallel exclusive scan -> bucket fill ---

__global__ void deg_kernel(const int* __restrict__ dst, int* __restrict__ deg, int E) {
    int i = blockIdx.x * blockDim.x + threadIdx.x;
    int stride = gridDim.x * blockDim.x;
    for (int e = i; e < E; e += stride)
        atomicAdd(&deg[dst[e]], 1);
}

__global__ void dinv_kernel(const int* __restrict__ deg, float* __restrict__ dinv, int n) {
    int i = blockIdx.x * blockDim.x + threadIdx.x;
    if (i < n) dinv[i] = rsqrtf((float)deg[i] + 1.0f);   // +1 = self-loop
}

// phase 1: per-tile sums
__global__ void scan_phase1(const int* __restrict__ deg, int* __restrict__ tileSums, int n) {
    __shared__ int red[256];
    int t = threadIdx.x;
    int i0 = blockIdx.x * SCAN_TILE + t * 8;
    int s = 0;
#pragma unroll
    for (int j = 0; j < 8; ++j) {
        int i = i0 + j;
        if (i < n) s += deg[i];
    }
    red[t] = s;
    __syncthreads();
    for (int d = 128; d > 0; d >>= 1) {
        if (t < d) red[t] += red[t + d];
        __syncthreads();
    }
    if (t == 0) tileSums[blockIdx.x] = red[0];
}

// phase 2: single small block exclusive-scans the tile sums (nTiles <= 256)
__global__ void scan_phase2(int* __restrict__ tileSums, int nTiles) {
    __shared__ int sh[256];
    int t = threadIdx.x;
    int v = (t < nTiles) ? tileSums[t] : 0;
    sh[t] = v;
    __syncthreads();
    for (int d = 1; d < 256; d <<= 1) {
        int u = (t >= d) ? sh[t - d] : 0;
        __syncthreads();
        sh[t] += u;
        __syncthreads();
    }
    if (t < nTiles) tileSums[t] = sh[t] - v;   // exclusive
}

// phase 3: intra-tile exclusive scan + tile base -> off[] and cursor[]
__global__ void scan_phase3(const int* __restrict__ deg, const int* __restrict__ tileSums,
                            int* __restrict__ off, int* __restrict__ cursor, int n, int E) {
    __shared__ int sh[256];
    int t = threadIdx.x;
    int i0 = blockIdx.x * SCAN_TILE + t * 8;
    int v[8];
    int s = 0;
#pragma unroll
    for (int j = 0; j < 8; ++j) {
        int i = i0 + j;
        v[j] = (i < n) ? deg[i] : 0;
        s += v[j];
    }
    sh[t] = s;
    __syncthreads();
    for (int d = 1; d < 256; d <<= 1) {
        int u = (t >= d) ? sh[t - d] : 0;
        __syncthreads();
        sh[t] += u;
        __syncthreads();
    }
    int run = tileSums[blockIdx.x] + sh[t] - s;
#pragma unroll
    for (int j = 0; j < 8; ++j) {
        int i = i0 + j;
        if (i < n) { off[i] = run; cursor[i] = run; run += v[j]; }
    }
    if (blockIdx.x == 0 && t == 0) off[n] = E;
}

// fill CSR: for each edge, place (src, dinv[src]*dinv[dst]) into dst's bucket
__global__ void fill_csr(const int* __restrict__ src, const int* __restrict__ dst,
                         const float* __restrict__ dinv, int* __restrict__ cursor,
                         float2* __restrict__ csr, int E) {
    int i = blockIdx.x * blockDim.x + threadIdx.x;
    int stride = gridDim.x * blockDim.x;
    for (int e = i; e < E; e += stride) {
        int s = src[e];
        int d = dst[e];
        float w = dinv[s] * dinv[d];
        int pos = atomicAdd(&cursor[d], 1);
        csr[pos] = make_float2(__int_as_float(s), w);
    }
}

// ---- per-layer dense GEMM (lin = h @ W) --------------------------------------

template<int FIN, int FOUT>
__global__ void gemm_kernel(const float* __restrict__ h, const float* __restrict__ W,
                            float* __restrict__ lin, int n) {
    __shared__ float sW[FIN * FOUT];
    for (int i = threadIdx.x; i < FIN * FOUT; i += blockDim.x) sW[i] = W[i];
    __syncthreads();
    constexpr int ROWS = 256 / FOUT;
    int f = threadIdx.x % FOUT;
    int r = threadIdx.x / FOUT;
    int row = blockIdx.x * ROWS + r;
    if (row >= n) return;
    const float* hr = h + (size_t)row * FIN;
    float acc = 0.f;
#pragma unroll
    for (int k = 0; k < FIN; ++k) acc = fmaf(hr[k], sW[k * FOUT + f], acc);
    lin[(size_t)row * FOUT + f] = acc;
}

// ---- fused aggregation: h = tanh(dinv^2*lin[i] + sum_e w*lin[src] + b) -------

template<int FOUT>
__global__ void gather_tanh(const int* __restrict__ off, const float2* __restrict__ csr,
                            const float* __restrict__ lin, const float* __restrict__ dinv,
                            const float* __restrict__ b, float* __restrict__ h, int n) {
    constexpr int GPB = 256 / FOUT;
    int g = blockIdx.x * GPB + threadIdx.x / FOUT;
    int f = threadIdx.x % FOUT;
    if (g >= n) return;
    int rb = off[g], re = off[g + 1];
    float dv = dinv[g];
    float acc = dv * dv * lin[(size_t)g * FOUT + f];
#pragma unroll 2
    for (int e = rb; e < re; ++e) {
        float2 p = csr[e];
        int s = __float_as_int(p.x);
        acc = fmaf(p.y, lin[(size_t)s * FOUT + f], acc);
    }
    h[(size_t)g * FOUT + f] = tanhf(acc + b[f]);
}

// ---- classifier: out = h @ Wc + bc  (8 -> 2) ---------------------------------

__global__ void classifier_kernel(const float* __restrict__ h, const float* __restrict__ Wc,
                                  const float* __restrict__ bc, float* __restrict__ out, int n) {
    int i = blockIdx.x * blockDim.x + threadIdx.x;
    if (i >= n) return;
    const float* hr = h + (size_t)i * 8;
    float a0 = bc[0], a1 = bc[1];
#pragma unroll
    for (int k = 0; k < 8; ++k) {
        float v = hr[k];
        a0 = fmaf(v, Wc[k * 2 + 0], a0);
        a1 = fmaf(v, Wc[k * 2 + 1], a1);
    }
    out[(size_t)i * 2 + 0] = a0;
    out[(size_t)i * 2 + 1] = a1;
}

// ---- launch ------------------------------------------------------------------

extern "C" void kernel_launch(void* const* d_in, const int* in_sizes, int n_in,
                              void* d_out, int out_size, void* d_ws, size_t ws_size,
                              hipStream_t stream) {
    const float* x  = (const float*)d_in[0];
    const int*   ei = (const int*)d_in[1];
    const float* W1 = (const float*)d_in[2];  const float* b1 = (const float*)d_in[3];
    const float* W2 = (const float*)d_in[4];  const float* b2 = (const float*)d_in[5];
    const float* W3 = (const float*)d_in[6];  const float* b3 = (const float*)d_in[7];
    const float* W4 = (const float*)d_in[8];  const float* b4 = (const float*)d_in[9];
    const float* Wc = (const float*)d_in[10]; const float* bc = (const float*)d_in[11];

    float* out  = (float*)d_out;                      // [N,2]
    float* hout = out + (size_t)2 * N_NODES;          // [N,8]

    const int n = N_NODES;
    const int E = in_sizes[1] / 2;
    const int* src = ei;
    const int* dst = ei + E;
    const int nTiles = (n + SCAN_TILE - 1) / SCAN_TILE;   // 49

    char* w = (char*)d_ws;
    int*    deg      = (int*)w;     w += (size_t)n * 4;
    float*  dinv     = (float*)w;   w += (size_t)n * 4;
    int*    off      = (int*)w;     w += (size_t)(n + 1) * 4;
    int*    cursor   = (int*)w;     w += (size_t)n * 4;
    int*    tileSums = (int*)w;     w += (size_t)256 * 4;
    float2* csr      = (float2*)w;  w += (size_t)E * 8;
    float*  lin      = (float*)w;   w += (size_t)n * 64 * 4;
    float*  hA       = (float*)w;   w += (size_t)n * 64 * 4;
    float*  hB       = (float*)w;   w += (size_t)n * 32 * 4;

    hipMemsetAsync(deg, 0, n * sizeof(int), stream);
    deg_kernel<<<2048, 256, 0, stream>>>(dst, deg, E);
    dinv_kernel<<<(n + 255) / 256, 256, 0, stream>>>(deg, dinv, n);
    scan_phase1<<<nTiles, 256, 0, stream>>>(deg, tileSums, n);
    scan_phase2<<<1, 256, 0, stream>>>(tileSums, nTiles);
    scan_phase3<<<nTiles, 256, 0, stream>>>(deg, tileSums, off, cursor, n, E);
    fill_csr<<<2048, 256, 0, stream>>>(src, dst, dinv, cursor, csr, E);

    // layer 1: x[34] -> hA[64]
    gemm_kernel<34, 64><<<(n + 3) / 4, 256, 0, stream>>>(x, W1, lin, n);
    gather_tanh<64><<<(n + 3) / 4, 256, 0, stream>>>(off, csr, lin, dinv, b1, hA, n);

    // layer 2: hA[64] -> hB[32]
    gemm_kernel<64, 32><<<(n + 7) / 8, 256, 0, stream>>>(hA, W2, lin, n);
    gather_tanh<32><<<(n + 7) / 8, 256, 0, stream>>>(off, csr, lin, dinv, b2, hB, n);

    // layer 3: hB[32] -> hA[16]
    gemm_kernel<32, 16><<<(n + 15) / 16, 256, 0, stream>>>(hB, W3, lin, n);
    gather_tanh<16><<<(n + 15) / 16, 256, 0, stream>>>(off, csr, lin, dinv, b3, hA, n);

    // layer 4: hA[16] -> hout[8]
    gemm_kernel<16, 8><<<(n + 31) / 32, 256, 0, stream>>>(hA, W4, lin, n);
    gather_tanh<8><<<(n + 31) / 32, 256, 0, stream>>>(off, csr, lin, dinv, b4, hout, n);

    // classifier
    classifier_kernel<<<(n + 255) / 256, 256, 0, stream>>>(hout, Wc, bc, out, n);
}